// Round 15
// baseline (48.662 us; speedup 1.0000x reference)
//
#include <hip/hip_runtime.h>
#include <math.h>

// GraphGenerator: radius-graph adjacency, OR over {0,0.25,0.5,0.75}*domain
// wrapped shifts, diagonal excluded. Output [N,N] int32 0/1.
//
// Golden ("ref=np") — PROVEN in R7 (absmax 0):
//   sq   = ((x*x) + (y*y)) + (z*z)          separately rounded (contract off!)
//   dot  = fma(z,z', fma(y,y', rn(x*x')))   sgemm sequential-k FMA chain
//   d2   = rn(rn(sq_i + sq_j) - rn(2*dot))
//   pred = d2 <= 0.01f ; wrap = fmodf(rn(x + rn(f*d)), d)
//
// Min-image prefilter (R8-proven): min-image d2 lower-bounds all variants and
// is achieved by one of them (seam argument); fast/golden chains differ
// < 3e-5, so outside the band the fast decision equals the golden OR;
// in-band pairs rerun the exact R7 chain from sp.
// R10-R14 lessons: store pattern/NT/burst ~neutral; fold trick (-2.6us) and
// VALU trims are the live lever; symmetry-halving costed out as a wash
// (transpose LDS issue ~= VALU saved).
// R15 change: predicate trim — b = d2m <= RR+EPS (correct for all non-band
// lanes), band = b && (d2m > RR-EPS). 2 cmps replace cmp+sub+cmp-abs.

__global__ __launch_bounds__(256) void gg_shift_kernel(
    const float* __restrict__ pos, const float* __restrict__ dom,
    float4* __restrict__ sp, int n)
{
#pragma clang fp contract(off)
    int i = blockIdx.x * blockDim.x + threadIdx.x;
    if (i >= n) return;
    float x = pos[3 * i + 0];
    float y = pos[3 * i + 1];
    float z = pos[3 * i + 2];
    float dx = dom[0], dy = dom[1], dz = dom[2];
#pragma unroll
    for (int k = 0; k < 4; ++k) {
        float sx, sy, sz;
        if (k == 0) {
            sx = x; sy = y; sz = z;
        } else {
            float f = 0.25f * (float)k;
            sx = fmodf(x + f * dx, dx);
            sy = fmodf(y + f * dy, dy);
            sz = fmodf(z + f * dz, dz);
        }
        float sq = ((sx * sx) + (sy * sy)) + (sz * sz);
        sp[(size_t)i * 4 + k] = make_float4(sx, sy, sz, sq);
    }
}

// Tile: 32 i-rows x 256 j-cols per 256-thread block (R13/R14 structure).
__global__ __launch_bounds__(256) void gg_adj_kernel(
    const float4* __restrict__ sp, const float* __restrict__ dom,
    int* __restrict__ out, int n)
{
    const int tid = threadIdx.x;
    const int tj = tid & 63;
    const int ti = tid >> 6;
    const int jbase = blockIdx.x * 256 + tj * 4;
    const int ibase = blockIdx.y * 32;
    const bool hasdiag = ((blockIdx.y >> 3) == blockIdx.x);

    const float hd0 = 0.5f * dom[0];   // exact (power-of-2 scale)
    const float hd1 = 0.5f * dom[1];
    const float hd2 = 0.5f * dom[2];

    __shared__ float4 si[32][4];   // i-tile: 4 variants (slow path needs all)
    for (int t = tid; t < 128; t += 256)
        si[t >> 2][t & 3] = sp[(size_t)(ibase + (t >> 2)) * 4 + (t & 3)];

    float4 jd0[4];                 // j-side raw coords (variant 0)
#pragma unroll
    for (int p = 0; p < 4; ++p)
        jd0[p] = sp[(size_t)(jbase + p) * 4 + 0];

    __syncthreads();

    const float RR   = 0.01f;            // f32(0.1*0.1)
    const float RRpE = 0.01f + 3e-5f;    // wide accept
    const float RRmE = 0.01f - 3e-5f;    // strict accept

    int4 resbuf[8];                // all results, then burst-store

#pragma unroll
    for (int iter = 0; iter < 8; ++iter) {
        const int irow = iter * 4 + ti;
        const float4 i0 = si[irow][0];       // LDS broadcast, raw coords

        int* r = &resbuf[iter].x;
#pragma unroll
        for (int p = 0; p < 4; ++p) {
            // fold: min(|d|, dom-|d|) = hd - |(|d| - hd)|  (abs mods free)
            const float dxv = i0.x - jd0[p].x;
            const float dyv = i0.y - jd0[p].y;
            const float dzv = i0.z - jd0[p].z;
            const float tx = fabsf(dxv) - hd0;
            const float ty = fabsf(dyv) - hd1;
            const float tz = fabsf(dzv) - hd2;
            const float mx = hd0 - fabsf(tx);
            const float my = hd1 - fabsf(ty);
            const float mz = hd2 - fabsf(tz);
            const float d2m = mx * mx + my * my + mz * mz;  // contraction ok
            // wide accept is golden-correct for all non-band lanes
            bool b = d2m <= RRpE;
            if (__builtin_expect(b && (d2m > RRmE), 0)) {
                // band: exact golden chain over all 4 variants (R7-proven)
#pragma clang fp contract(off)
                b = false;
#pragma unroll 1
                for (int k = 0; k < 4; ++k) {
                    const float4 iv = si[irow][k];
                    const float4 jv = sp[(size_t)(jbase + p) * 4 + k];
                    float dot = __builtin_fmaf(iv.z, jv.z,
                                __builtin_fmaf(iv.y, jv.y, iv.x * jv.x));
                    float d2 = (iv.w + jv.w) - (2.0f * dot);
                    if (d2 <= RR) b = true;
                }
            }
            r[p] = b ? 1 : 0;
        }
    }

    // Rare diagonal fixup (32 of 8192 blocks).
    if (hasdiag) {
#pragma unroll
        for (int iter = 0; iter < 8; ++iter) {
            const int i = ibase + iter * 4 + ti;
            if (i == jbase + 0) resbuf[iter].x = 0;
            if (i == jbase + 1) resbuf[iter].y = 0;
            if (i == jbase + 2) resbuf[iter].z = 0;
            if (i == jbase + 3) resbuf[iter].w = 0;
        }
    }

    // Burst: 8 back-to-back dwordx4 stores.
#pragma unroll
    for (int iter = 0; iter < 8; ++iter) {
        const int i = ibase + iter * 4 + ti;
        *reinterpret_cast<int4*>(&out[(size_t)i * n + jbase]) = resbuf[iter];
    }
}

extern "C" void kernel_launch(void* const* d_in, const int* in_sizes, int n_in,
                              void* d_out, int out_size, void* d_ws, size_t ws_size,
                              hipStream_t stream) {
    const float* pos = (const float*)d_in[0];   // [N,3] float32
    const float* dom = (const float*)d_in[1];   // [3] float32
    const int n = in_sizes[0] / 3;              // 8192

    float4* sp = (float4*)d_ws;                 // [N][4] float4 = 512 KB
    int* out = (int*)d_out;                     // [N,N] int32 0/1

    gg_shift_kernel<<<(n + 255) / 256, 256, 0, stream>>>(pos, dom, sp, n);

    dim3 grid(n / 256, n / 32);                 // (32, 256)
    gg_adj_kernel<<<grid, 256, 0, stream>>>(sp, dom, out, n);
}

// Round 16
// 48.213 us; speedup vs baseline: 1.0093x; 1.0093x over previous
//
#include <hip/hip_runtime.h>
#include <math.h>

// GraphGenerator: radius-graph adjacency, OR over {0,0.25,0.5,0.75}*domain
// wrapped shifts, diagonal excluded. Output [N,N] int32 0/1.
//
// Golden ("ref=np") — PROVEN in R7 (absmax 0):
//   sq   = ((x*x) + (y*y)) + (z*z)          separately rounded (contract off!)
//   dot  = fma(z,z', fma(y,y', rn(x*x')))   sgemm sequential-k FMA chain
//   d2   = rn(rn(sq_i + sq_j) - rn(2*dot))
//   pred = d2 <= 0.01f ; wrap = fmodf(rn(x + rn(f*d)), d)
//
// Min-image prefilter (R8-proven): min-image d2 lower-bounds all variants and
// is achieved by one of them (seam argument); fast/golden chains differ
// < 3e-5, so outside the +-3e-5 band the fast decision equals the golden OR;
// in-band pairs rerun the exact R7 chain from sp.
//
// FINAL (R14 structure, 47.7us): best of R8-R15.
//   - store pattern / NT / burst-depth / row-contiguous: all ~neutral (R10-R13)
//   - fold trick min(a,dom-a) = hd-|a-hd| via free abs input-mods: -2.6us (R14)
//   - predicate trim (R15): regressed, reverted
//   - symmetry-halving: costed as a wash (transpose issue ~= VALU saved)
// Ledger: 268.4MB stores @ fill-kernel 7.1TB/s = 37.8us floor + ~2us shift +
// ~2us launch/tail + ~5us exposed VALU ~= 47us ~= measured. Roofline.

__global__ __launch_bounds__(256) void gg_shift_kernel(
    const float* __restrict__ pos, const float* __restrict__ dom,
    float4* __restrict__ sp, int n)
{
#pragma clang fp contract(off)
    int i = blockIdx.x * blockDim.x + threadIdx.x;
    if (i >= n) return;
    float x = pos[3 * i + 0];
    float y = pos[3 * i + 1];
    float z = pos[3 * i + 2];
    float dx = dom[0], dy = dom[1], dz = dom[2];
#pragma unroll
    for (int k = 0; k < 4; ++k) {
        float sx, sy, sz;
        if (k == 0) {
            sx = x; sy = y; sz = z;
        } else {
            float f = 0.25f * (float)k;
            sx = fmodf(x + f * dx, dx);
            sy = fmodf(y + f * dy, dy);
            sz = fmodf(z + f * dz, dz);
        }
        float sq = ((sx * sx) + (sy * sy)) + (sz * sz);
        sp[(size_t)i * 4 + k] = make_float4(sx, sy, sz, sq);
    }
}

// Tile: 32 i-rows x 256 j-cols per 256-thread block (R13 structure).
__global__ __launch_bounds__(256) void gg_adj_kernel(
    const float4* __restrict__ sp, const float* __restrict__ dom,
    int* __restrict__ out, int n)
{
    const int tid = threadIdx.x;
    const int tj = tid & 63;
    const int ti = tid >> 6;
    const int jbase = blockIdx.x * 256 + tj * 4;
    const int ibase = blockIdx.y * 32;
    const bool hasdiag = ((blockIdx.y >> 3) == blockIdx.x);

    const float hd0 = 0.5f * dom[0];   // exact (power-of-2 scale)
    const float hd1 = 0.5f * dom[1];
    const float hd2 = 0.5f * dom[2];

    __shared__ float4 si[32][4];   // i-tile: 4 variants (slow path needs all)
    for (int t = tid; t < 128; t += 256)
        si[t >> 2][t & 3] = sp[(size_t)(ibase + (t >> 2)) * 4 + (t & 3)];

    float4 jd0[4];                 // j-side raw coords (variant 0)
#pragma unroll
    for (int p = 0; p < 4; ++p)
        jd0[p] = sp[(size_t)(jbase + p) * 4 + 0];

    __syncthreads();

    const float RR  = 0.01f;       // f32(0.1*0.1)
    const float EPS = 3e-5f;       // band half-width

    int4 resbuf[8];                // all results, then burst-store

#pragma unroll
    for (int iter = 0; iter < 8; ++iter) {
        const int irow = iter * 4 + ti;
        const float4 i0 = si[irow][0];       // LDS broadcast, raw coords

        int* r = &resbuf[iter].x;
#pragma unroll
        for (int p = 0; p < 4; ++p) {
            // fold: min(|d|, dom-|d|) = hd - |(|d| - hd)|  (abs mods free)
            const float dxv = i0.x - jd0[p].x;
            const float dyv = i0.y - jd0[p].y;
            const float dzv = i0.z - jd0[p].z;
            const float tx = fabsf(dxv) - hd0;
            const float ty = fabsf(dyv) - hd1;
            const float tz = fabsf(dzv) - hd2;
            const float mx = hd0 - fabsf(tx);
            const float my = hd1 - fabsf(ty);
            const float mz = hd2 - fabsf(tz);
            const float d2m = mx * mx + my * my + mz * mz;  // contraction ok
            bool b = d2m <= RR;
            if (__builtin_expect(fabsf(d2m - RR) <= EPS, 0)) {
                // band: exact golden chain over all 4 variants (R7-proven)
#pragma clang fp contract(off)
                b = false;
#pragma unroll 1
                for (int k = 0; k < 4; ++k) {
                    const float4 iv = si[irow][k];
                    const float4 jv = sp[(size_t)(jbase + p) * 4 + k];
                    float dot = __builtin_fmaf(iv.z, jv.z,
                                __builtin_fmaf(iv.y, jv.y, iv.x * jv.x));
                    float d2 = (iv.w + jv.w) - (2.0f * dot);
                    if (d2 <= RR) b = true;
                }
            }
            r[p] = b ? 1 : 0;
        }
    }

    // Rare diagonal fixup (32 of 8192 blocks).
    if (hasdiag) {
#pragma unroll
        for (int iter = 0; iter < 8; ++iter) {
            const int i = ibase + iter * 4 + ti;
            if (i == jbase + 0) resbuf[iter].x = 0;
            if (i == jbase + 1) resbuf[iter].y = 0;
            if (i == jbase + 2) resbuf[iter].z = 0;
            if (i == jbase + 3) resbuf[iter].w = 0;
        }
    }

    // Burst: 8 back-to-back dwordx4 stores.
#pragma unroll
    for (int iter = 0; iter < 8; ++iter) {
        const int i = ibase + iter * 4 + ti;
        *reinterpret_cast<int4*>(&out[(size_t)i * n + jbase]) = resbuf[iter];
    }
}

extern "C" void kernel_launch(void* const* d_in, const int* in_sizes, int n_in,
                              void* d_out, int out_size, void* d_ws, size_t ws_size,
                              hipStream_t stream) {
    const float* pos = (const float*)d_in[0];   // [N,3] float32
    const float* dom = (const float*)d_in[1];   // [3] float32
    const int n = in_sizes[0] / 3;              // 8192

    float4* sp = (float4*)d_ws;                 // [N][4] float4 = 512 KB
    int* out = (int*)d_out;                     // [N,N] int32 0/1

    gg_shift_kernel<<<(n + 255) / 256, 256, 0, stream>>>(pos, dom, sp, n);

    dim3 grid(n / 256, n / 32);                 // (32, 256)
    gg_adj_kernel<<<grid, 256, 0, stream>>>(sp, dom, out, n);
}